// Round 6
// baseline (406.339 us; speedup 1.0000x reference)
//
#include <hip/hip_runtime.h>
#include <cmath>
#include <cstdint>
#include <vector>
#include <cstdlib>
#include <algorithm>

#define WGB 256

typedef float vf4 __attribute__((ext_vector_type(4)));   // native vector: OK for nontemporal builtins

// ---------------- constexpr problem metadata (evaluated identically host+device) ----------------
struct TripleMeta { int l,l1,l2,d,d1,d2,form,dp4,cgR,cgL,uv; };
struct AllMeta { TripleMeta t[48]; int nT, cgTotal, uvTotal; };

constexpr AllMeta build_meta() {
  AllMeta M{};
  const int LSl[5] = {0,2,4,6,8};
  int k=0, cg=0;
  for (int a=0;a<5;a++){ const int l=LSl[a];
    for (int b=0;b<5;b++){ const int l1=LSl[b];
      for (int l2=l1;l2<=8;l2+=2){
        if (!((l2-l1)<=l && l<=(l1+l2))) continue;
        TripleMeta m{};
        m.l=l; m.l1=l1; m.l2=l2;
        m.d=2*l+1; m.d1=2*l1+1; m.d2=2*l2+1;
        m.form = (l1==0) ? ((l2==0)?2:1) : 0;   // 0=A (l1>0), 1=B (l1==0,l2>0), 2=D (0,0,0)
        m.dp4 = ((m.d+3)/4)*4;
        m.cgR = cg; cg += m.d*m.d1*m.d2;
        M.t[k] = m; k++;
      } } }
  M.nT=k; M.cgTotal=cg;
  int cgl=cg;
  for (int i=0;i<k;i++){ M.t[i].cgL=cgl; cgl += M.t[i].d*M.t[i].d1*M.t[i].d2; }
  int uv=0;
  for (int i=0;i<k;i++){
    if (M.t[i].form==0){ M.t[i].uv=uv; uv += 4*M.t[i].dp4; }
    else if (M.t[i].form==1){ M.t[i].uv=uv; uv += 2*M.t[i].dp4; }
  }
  M.uvTotal=uv;
  return M;
}

constexpr AllMeta META_H = build_meta();            // host view
static_assert(META_H.nT==42, "nT");
static_assert(META_H.cgTotal==52334, "cgTotal");
static_assert(META_H.uvTotal==2048, "uvTotal");

__device__ constexpr AllMeta META = build_meta();   // device view (identical values)

constexpr int CG_TOTAL  = 52334;
constexpr int UVS       = 2048;      // U/V slot-table stride (floats) per (ab,c)
constexpr int ZTOT      = 4520;      // z-buffer floats in LDS (8*d^2 summed)
constexpr int NUC       = 417;       // fused U work items (373 FormA + 44 FormB)
constexpr int NVC       = 1580;      // s2_prep V items per (ab,c)

__device__ constexpr int DL[5]     = {1,5,9,13,17};
__device__ constexpr int T0G[6]    = {0,5,13,23,33,42};       // triple ranges per output-l group
__device__ constexpr int RHNB[5]   = {163840,196608,1015808,3670016,9207808}; // rh_n out offsets
__device__ constexpr int CBASE[5]  = {352,312,240,136,0};     // phase-3 column base per li
// z-buffer: per-li base, 8*d^2 each; all %4==0 for float4 copy
__device__ constexpr int ZB[5]     = {0,8,208,856,2208};
__device__ constexpr int LEN5[5]   = {8,200,648,1352,2312};
__device__ constexpr int C4[6]     = {0,2,52,214,552,1130};   // cumulative float4 counts

// ---------------- kernel 1: V table, one element per thread ----------------
__global__ __launch_bounds__(WGB) void s2_prep(
    const float* __restrict__ w2, const float* __restrict__ w4,
    const float* __restrict__ w6, const float* __restrict__ w8,
    const float* __restrict__ cg, const int2* __restrict__ wiv,
    float* __restrict__ V)
{
  const int idx = blockIdx.x * WGB + threadIdx.x;
  if (idx >= 32*NVC) return;
  const int abc = idx / NVC;
  const int it  = idx - abc*NVC;
  const int ab = abc >> 3, c = abc & 7;
  const int2 w = wiv[it];
  const int dst = w.y & 0xFFF;
  const int p   = (w.y>>12)&1, q = (w.y>>13)&1;
  const int l1i = (w.y>>14)&3, l2i = (w.y>>16)&3;
  const int d1  = (w.y>>18)&31, d2 = (w.y>>23)&31;
  const float* R = cg + w.x;
  const float* ws[4] = {w2,w4,w6,w8};
  const float* wB = ws[l2i] + ((ab*2+q)*8 + c)*d2;
  float s = 0.f;
  if (d1) {   // FormA
    const float* wA = ws[l1i] + ((ab*2+p)*8 + c)*d1;
    for (int a=0;a<d1;a++){
      float t = 0.f;
      for (int j=0;j<d2;j++) t += wB[j]*R[a*d2+j];
      s += wA[a]*t;
    }
  } else {    // FormB
    for (int j=0;j<d2;j++) s += wB[j]*R[j];
  }
  V[abc*UVS + dst] = s;   // normal store: V is L2-reused by s2_main
}

// ---------------- fused phase 1+2: one (t,k1) item -> 4 (or 2) U values ----------------
template<int D1>
__device__ __forceinline__ void u_itemA(const float* __restrict__ Lp, const float* xb,
    float* Ush, int dst, int dstr, int xo1, int xo2, int d2)
{
  float x1r[2*D1];
  #pragma unroll
  for (int j=0;j<2*D1;j++) x1r[j] = xb[xo1+j];
  float a00=0.f,a01=0.f,a10=0.f,a11=0.f;
  for (int b=0;b<d2;b++){
    float in0=0.f, in1=0.f;
    const float* Lb = Lp + b*D1;       // contiguous slab
    #pragma unroll
    for (int j=0;j<D1;j++){ const float lv=Lb[j]; in0+=lv*x1r[j]; in1+=lv*x1r[D1+j]; }
    const float xq0=xb[xo2+b], xq1=xb[xo2+d2+b];
    a00+=xq0*in0; a01+=xq1*in0; a10+=xq0*in1; a11+=xq1*in1;
  }
  Ush[dst]=a00; Ush[dst+dstr]=a01; Ush[dst+2*dstr]=a10; Ush[dst+3*dstr]=a11;
}

__device__ __forceinline__ void u_item(const int4 w, const float* __restrict__ cg,
                                       const float* xb, float* Ush)
{
  const float* Lp = cg + w.x;
  const int dst = w.y & 0xFFFF, dstr = ((unsigned)w.y) >> 16;
  const int xo1 = w.z & 0xFF, xo2 = (w.z>>8)&0xFF;
  const int d1 = (w.z>>16)&0x3F, d2 = ((unsigned)w.z)>>22;
  if (d1 == 0){                         // FormB: U'[q][k1] = sum_b L[k1,b]*x2[q,b]
    float a0=0.f, a1=0.f;
    for (int b=0;b<d2;b++){ const float lv=Lp[b]; a0+=lv*xb[xo2+b]; a1+=lv*xb[xo2+d2+b]; }
    Ush[dst]=a0; Ush[dst+dstr]=a1;
    return;
  }
  switch(d1){
    case 5:  u_itemA<5>(Lp,xb,Ush,dst,dstr,xo1,xo2,d2); break;
    case 9:  u_itemA<9>(Lp,xb,Ush,dst,dstr,xo1,xo2,d2); break;
    case 13: u_itemA<13>(Lp,xb,Ush,dst,dstr,xo1,xo2,d2); break;
    default: u_itemA<17>(Lp,xb,Ush,dst,dstr,xo1,xo2,d2); break;
  }
}

// ---------------- phase-3 column worker (one (c, l, k2) column) -> z into LDS ----------------
template<int LI>
__device__ __forceinline__ float col_work(int k2, float rh0c, float c000,
    const float* __restrict__ Vc, const float* Ush,
    float* zsh, int zb)
{
  constexpr int d   = (LI==0)?1:(LI==1)?5:(LI==2)?9:(LI==3)?13:17;
  constexpr int np4 = (d+3)/4;
  float4 za[np4];
  #pragma unroll
  for (int i=0;i<np4;i++) za[i] = make_float4(0.f,0.f,0.f,0.f);
  #pragma unroll
  for (int t=T0G[LI]; t<T0G[LI+1]; t++){
    const auto &m = META.t[t];
    if (m.form==2){
      za[0].x += rh0c*rh0c*c000;
    } else {
      const int npr = (m.form==0)?4:2;
      #pragma unroll
      for (int pr=0;pr<npr;pr++){
        float v = Vc[m.uv + pr*m.dp4 + k2];
        if (m.form==1) v *= rh0c;
        const float4* Up = reinterpret_cast<const float4*>(Ush + m.uv + pr*m.dp4);
        #pragma unroll
        for (int rr=0;rr<np4;rr++){
          float4 u = Up[rr];           // wave-uniform LDS broadcast
          za[rr].x += u.x*v; za[rr].y += u.y*v; za[rr].z += u.z*v; za[rr].w += u.w*v;
        }
      }
    }
  }
  float s = 0.f;
  #pragma unroll
  for (int rr=0;rr<np4;rr++){
    const float vals[4] = {za[rr].x, za[rr].y, za[rr].z, za[rr].w};
    #pragma unroll
    for (int e=0;e<4;e++){
      const int k1 = 4*rr+e;
      if (k1 < d){
        zsh[zb + k1*d + k2] = vals[e];   // LDS scatter; global store is phase 3b
        s += vals[e]*vals[e];
      }
    }
  }
  return s;
}

// ---------------- kernel 2: main, one block per (ab,n) ----------------
__global__ __launch_bounds__(WGB,5) void s2_main(
    const float* __restrict__ x0, const float* __restrict__ x2, const float* __restrict__ x4,
    const float* __restrict__ x6, const float* __restrict__ x8,
    const float* __restrict__ w0, const float* __restrict__ bias,
    const float* __restrict__ cg, const int4* __restrict__ wiU,
    const float* __restrict__ V, float* __restrict__ out, float c000)
{
  __shared__ alignas(16) float SH[ZTOT + UVS];   // [z | U]
  __shared__ float xb[104];
  __shared__ float rh0s[8];
  __shared__ float fpart[360];
  const int tid = threadIdx.x;
  const int bid = blockIdx.x;
  const int ab  = bid >> 10;
  const int n   = bid & 1023;
  float* Ush = SH + ZTOT;

  // ---- phase 0: stage x, compute rh0 (= x0·w0 + bias, the l=0 conv scalar) ----
  if (tid < 5)        xb[tid]           = x0[bid*5  + tid];
  else if (tid < 15)  xb[8  + (tid-5)]  = x2[bid*10 + (tid-5)];
  else if (tid < 33)  xb[18 + (tid-15)] = x4[bid*18 + (tid-15)];
  else if (tid < 59)  xb[36 + (tid-33)] = x6[bid*26 + (tid-33)];
  else if (tid < 93)  xb[62 + (tid-59)] = x8[bid*34 + (tid-59)];
  else if (tid >= 96 && tid < 104) {
    const int c = tid - 96;
    float s = bias[ab*8 + c];
    for (int i=0;i<5;i++) s += x0[bid*5+i] * w0[(ab*5+i)*8 + c];
    rh0s[c] = s;
  }
  __syncthreads();

  // ---- phase 1+2 fused: U[pq][k1] = sum_b x2[q,b] * (sum_j L[k1,b,j]*x1[p,j]) ----
  // items host-sorted by cost desc; snake assignment for wave balance
  u_item(wiU[tid], cg, xb, Ush);
  {
    const int r = NUC-1-tid;
    if (r >= WGB) u_item(wiU[r], cg, xb, Ush);
  }
  __syncthreads();

  // ---- phase 3: z_l[k1,k2] = sum over rank terms U[k1]*V[k2]; z -> LDS ----
  const float* Vab = V + (ab*8)*UVS;
  for (int col=tid; col<360; col+=WGB){
    int li, c, k2;
    if (col < 136)      { li=4; c = col/17;            k2 = col - c*17; }
    else if (col < 240) { const int r=col-136; li=3; c=r/13; k2=r-c*13; }
    else if (col < 312) { const int r=col-240; li=2; c=r/9;  k2=r-c*9;  }
    else if (col < 352) { const int r=col-312; li=1; c=r/5;  k2=r-c*5;  }
    else                { li=0; c=col-352; k2=0; }
    const int d = DL[li];
    const float rh0c = rh0s[c];
    const float* Vc = Vab + c*UVS;
    const int zb = ZB[li] + c*d*d;
    float s;
    switch(li){
      case 4:  s = col_work<4>(k2, rh0c, c000, Vc, Ush, SH, zb); break;
      case 3:  s = col_work<3>(k2, rh0c, c000, Vc, Ush, SH, zb); break;
      case 2:  s = col_work<2>(k2, rh0c, c000, Vc, Ush, SH, zb); break;
      case 1:  s = col_work<1>(k2, rh0c, c000, Vc, Ush, SH, zb); break;
      default: s = col_work<0>(k2, rh0c, c000, Vc, Ush, SH, zb); break;
    }
    fpart[col] = s;
  }
  __syncthreads();

  // ---- phase 3b: coalesced vf4 copy LDS z -> global rh_n, NON-TEMPORAL ----
  // (outputs have zero reuse; nt keeps CG/V resident in the per-XCD L2)
  for (int i4 = tid; i4 < 1130; i4 += WGB){
    int li;
    if      (i4 < C4[1]) li = 0;
    else if (i4 < C4[2]) li = 1;
    else if (i4 < C4[3]) li = 2;
    else if (i4 < C4[4]) li = 3;
    else                 li = 4;
    const int r4 = i4 - C4[li];
    const vf4 v = *reinterpret_cast<const vf4*>(SH + ZB[li] + 4*r4);
    __builtin_nontemporal_store(v, reinterpret_cast<vf4*>(out + RHNB[li] + bid*LEN5[li] + 4*r4));
  }

  // ---- phase 4: feats reduce: n_l * sum z^2, layout (A,B, 5*N*C); nt store ----
  if (tid < 40){
    const int li = tid >> 3, c = tid & 7;
    const int d = DL[li];
    float s = 0.f;
    for (int k2=0;k2<d;k2++) s += fpart[CBASE[li] + c*d + k2];
    const double nl_d = 8.0*3.14159265358979323846*3.14159265358979323846/(double)(2*(2*li)+1);
    __builtin_nontemporal_store((float)nl_d * s, out + ab*40960 + li*8192 + n*8 + c);
  }
}

// ---------------- host: numpy MT19937 + legacy gauss, tables + CG upload at dlopen ----------------
namespace {

struct MTRng {
  uint32_t mt[624]; int mti;
  bool has_g; double g;
  void seed(uint32_t s){
    for (int pos=0; pos<624; pos++){ mt[pos]=s; s = 1812433253u*(s^(s>>30)) + (uint32_t)pos + 1u; }
    mti = 624; has_g=false; g=0.0;
  }
  uint32_t next32(){
    if (mti >= 624){
      for (int i=0;i<624;i++){
        uint32_t y = (mt[i]&0x80000000u) | (mt[(i+1)%624]&0x7fffffffu);
        mt[i] = mt[(i+397)%624] ^ (y>>1) ^ ((y&1u) ? 0x9908b0dfu : 0u);
      }
      mti = 0;
    }
    uint32_t y = mt[mti++];
    y ^= y>>11; y ^= (y<<7)&0x9d2c5680u; y ^= (y<<15)&0xefc60000u; y ^= y>>18;
    return y;
  }
  double rk_double(){
    uint32_t a = next32()>>5, b = next32()>>6;
    return (a*67108864.0 + b)/9007199254740992.0;
  }
  double gauss(){
    if (has_g){ has_g=false; return g; }
    double f,x1,x2,r2;
    do {
      x1 = 2.0*rk_double()-1.0;
      x2 = 2.0*rk_double()-1.0;
      r2 = x1*x1 + x2*x2;
    } while (r2 >= 1.0 || r2 == 0.0);
    f = std::sqrt(-2.0*std::log(r2)/r2);
    g = f*x1; has_g = true;
    return f*x2;
  }
};

constexpr int XOFS_H[5] = {0,8,18,36,62};

struct DeviceSetup {
  float* d_cg  = nullptr;   // [CG_R | CG_L]  (2*CG_TOTAL floats)
  float* d_v   = nullptr;   // 32 * UVS floats, rewritten by s2_prep every launch
  int4*  d_wiU = nullptr;
  int2*  d_wiv = nullptr;
  float  c000  = 0.f;
  DeviceSetup(){
    // CG tables, bit-faithful numpy RandomState(42)
    std::vector<float> h(2*CG_TOTAL);
    MTRng r; r.seed(42u);
    for (int i=0;i<2*CG_TOTAL;i++) h[i] = (float)(r.gauss()*0.1);
    c000 = h[META_H.t[0].cgL] * h[META_H.t[0].cgR];

    // fused U work items: one per (t,k1)
    std::vector<std::pair<int,int4>> tmp;
    for (int t=0;t<META_H.nT;t++){
      const TripleMeta &m = META_H.t[t];
      if (m.form==0){
        const int xo1 = XOFS_H[m.l1>>1], xo2 = XOFS_H[m.l2>>1];
        for (int k1=0;k1<m.d;k1++){
          int4 e;
          e.x = m.cgL + k1*m.d1*m.d2;
          e.y = (m.uv + k1) | (m.dp4<<16);
          e.z = xo1 | (xo2<<8) | (m.d1<<16) | (m.d2<<22);
          e.w = 0;
          tmp.push_back({m.d2*(2*m.d1+4), e});
        }
      } else if (m.form==1){
        const int xo2 = XOFS_H[m.l2>>1];
        for (int k1=0;k1<m.d;k1++){
          int4 e;
          e.x = m.cgL + k1*m.d2;
          e.y = (m.uv + k1) | (m.dp4<<16);
          e.z = (xo2<<8) | (0<<16) | (m.d2<<22);
          e.w = 0;
          tmp.push_back({2*m.d2, e});
        }
      }
    }
    if ((int)tmp.size() != NUC) std::abort();
    std::stable_sort(tmp.begin(), tmp.end(),
                     [](const std::pair<int,int4>&a, const std::pair<int,int4>&b){
                       return a.first > b.first; });
    std::vector<int4> wiU(NUC);
    for (int i=0;i<NUC;i++) wiU[i] = tmp[i].second;

    // V work items (per (ab,c); abc decoded in-kernel)
    std::vector<int2> wiv;
    for (int t=0;t<META_H.nT;t++){
      const TripleMeta &m = META_H.t[t];
      if (m.form==0){
        const int l1i = (m.l1>>1)-1, l2i = (m.l2>>1)-1;
        for (int pq=0;pq<4;pq++){
          const int p = pq>>1, q = pq&1;
          for (int k2=0;k2<m.d;k2++){
            int2 e;
            e.x = m.cgR + k2*m.d1*m.d2;
            e.y = (m.uv + pq*m.dp4 + k2) | (p<<12) | (q<<13) | (l1i<<14) | (l2i<<16)
                | (m.d1<<18) | (m.d2<<23);
            wiv.push_back(e);
          }
        }
      } else if (m.form==1){
        const int l2i = (m.l2>>1)-1;
        for (int q=0;q<2;q++){
          for (int k2=0;k2<m.d;k2++){
            int2 e;
            e.x = m.cgR + k2*m.d2;
            e.y = (m.uv + q*m.dp4 + k2) | (q<<13) | (l2i<<16) | (0<<18) | (m.d2<<23);
            wiv.push_back(e);
          }
        }
      }
    }
    if ((int)wiv.size() != NVC) std::abort();

    (void)hipMalloc((void**)&d_cg,  sizeof(float)*2*CG_TOTAL);
    (void)hipMalloc((void**)&d_v,   sizeof(float)*32*UVS);
    (void)hipMalloc((void**)&d_wiU, sizeof(int4)*NUC);
    (void)hipMalloc((void**)&d_wiv, sizeof(int2)*NVC);
    (void)hipMemcpy(d_cg,  h.data(),    sizeof(float)*2*CG_TOTAL, hipMemcpyHostToDevice);
    (void)hipMemcpy(d_wiU, wiU.data(),  sizeof(int4)*NUC,  hipMemcpyHostToDevice);
    (void)hipMemcpy(d_wiv, wiv.data(),  sizeof(int2)*NVC,  hipMemcpyHostToDevice);
  }
};
DeviceSetup g_dev;   // static init at dlopen: pure-CPU RNG + one-time uploads (outside graph capture)

} // namespace

extern "C" void kernel_launch(void* const* d_in, const int* in_sizes, int n_in,
                              void* d_out, int out_size, void* d_ws, size_t ws_size,
                              hipStream_t stream)
{
  (void)in_sizes; (void)n_in; (void)d_ws; (void)ws_size; (void)out_size;
  const float* x0   = (const float*)d_in[0];
  const float* w0   = (const float*)d_in[1];
  const float* x2   = (const float*)d_in[2];
  const float* w2   = (const float*)d_in[3];
  const float* x4   = (const float*)d_in[4];
  const float* w4   = (const float*)d_in[5];
  const float* x6   = (const float*)d_in[6];
  const float* w6   = (const float*)d_in[7];
  const float* x8   = (const float*)d_in[8];
  const float* w8   = (const float*)d_in[9];
  const float* bias = (const float*)d_in[10];
  float* out = (float*)d_out;

  const int prep_blocks = (32*NVC + WGB - 1) / WGB;
  s2_prep<<<dim3(prep_blocks), dim3(WGB), 0, stream>>>(w2,w4,w6,w8, g_dev.d_cg, g_dev.d_wiv, g_dev.d_v);
  s2_main<<<dim3(4096), dim3(WGB), 0, stream>>>(x0,x2,x4,x6,x8, w0, bias,
                                                g_dev.d_cg, g_dev.d_wiU,
                                                g_dev.d_v, out, g_dev.c000);
}

// Round 7
// 293.979 us; speedup vs baseline: 1.3822x; 1.3822x over previous
//
#include <hip/hip_runtime.h>
#include <cmath>
#include <cstdint>
#include <vector>
#include <cstdlib>
#include <algorithm>

#define WGB 256

typedef float vf4 __attribute__((ext_vector_type(4)));   // native vector: OK for nontemporal builtins

// ---------------- constexpr problem metadata (evaluated identically host+device) ----------------
struct TripleMeta { int l,l1,l2,d,d1,d2,form,dp4,cgR,cgL,uv; };
struct AllMeta { TripleMeta t[48]; int nT, cgTotal, uvTotal; };

constexpr AllMeta build_meta() {
  AllMeta M{};
  const int LSl[5] = {0,2,4,6,8};
  int k=0, cg=0;
  for (int a=0;a<5;a++){ const int l=LSl[a];
    for (int b=0;b<5;b++){ const int l1=LSl[b];
      for (int l2=l1;l2<=8;l2+=2){
        if (!((l2-l1)<=l && l<=(l1+l2))) continue;
        TripleMeta m{};
        m.l=l; m.l1=l1; m.l2=l2;
        m.d=2*l+1; m.d1=2*l1+1; m.d2=2*l2+1;
        m.form = (l1==0) ? ((l2==0)?2:1) : 0;   // 0=A (l1>0), 1=B (l1==0,l2>0), 2=D (0,0,0)
        m.dp4 = ((m.d+3)/4)*4;
        m.cgR = cg; cg += m.d*m.d1*m.d2;
        M.t[k] = m; k++;
      } } }
  M.nT=k; M.cgTotal=cg;
  int cgl=cg;
  for (int i=0;i<k;i++){ M.t[i].cgL=cgl; cgl += M.t[i].d*M.t[i].d1*M.t[i].d2; }
  int uv=0;
  for (int i=0;i<k;i++){
    if (M.t[i].form==0){ M.t[i].uv=uv; uv += 4*M.t[i].dp4; }
    else if (M.t[i].form==1){ M.t[i].uv=uv; uv += 2*M.t[i].dp4; }
  }
  M.uvTotal=uv;
  return M;
}

constexpr AllMeta META_H = build_meta();            // host view
static_assert(META_H.nT==42, "nT");
static_assert(META_H.cgTotal==52334, "cgTotal");
static_assert(META_H.uvTotal==2048, "uvTotal");

__device__ constexpr AllMeta META = build_meta();   // device view (identical values)

constexpr int CG_TOTAL  = 52334;
constexpr int UVS       = 2048;      // U/V slot-table stride (floats)
constexpr int ZTOT      = 4520;      // z-buffer floats in LDS (8*d^2 summed)
constexpr int NUC       = 417;       // fused U work items (373 FormA + 44 FormB)
constexpr int NVC       = 1580;      // s2_prep V items per (ab,c)
constexpr int XBS       = 104;       // per-voxel xb stride in LDS

__device__ constexpr int DL[5]     = {1,5,9,13,17};
__device__ constexpr int T0G[6]    = {0,5,13,23,33,42};       // triple ranges per output-l group
__device__ constexpr int RHNB[5]   = {163840,196608,1015808,3670016,9207808}; // rh_n out offsets
__device__ constexpr int CBASE[5]  = {352,312,240,136,0};     // phase-3 column base per li
// z-buffer: per-li base, 8*d^2 each; all %4==0 for float4 copy
__device__ constexpr int ZB[5]     = {0,8,208,856,2208};
__device__ constexpr int LEN5[5]   = {8,200,648,1352,2312};
__device__ constexpr int C4[6]     = {0,2,52,214,552,1130};   // cumulative float4 counts

// ---------------- kernel 1: V table, one element per thread ----------------
__global__ __launch_bounds__(WGB) void s2_prep(
    const float* __restrict__ w2, const float* __restrict__ w4,
    const float* __restrict__ w6, const float* __restrict__ w8,
    const float* __restrict__ cg, const int2* __restrict__ wiv,
    float* __restrict__ V)
{
  const int idx = blockIdx.x * WGB + threadIdx.x;
  if (idx >= 32*NVC) return;
  const int abc = idx / NVC;
  const int it  = idx - abc*NVC;
  const int ab = abc >> 3, c = abc & 7;
  const int2 w = wiv[it];
  const int dst = w.y & 0xFFF;
  const int p   = (w.y>>12)&1, q = (w.y>>13)&1;
  const int l1i = (w.y>>14)&3, l2i = (w.y>>16)&3;
  const int d1  = (w.y>>18)&31, d2 = (w.y>>23)&31;
  const float* R = cg + w.x;
  const float* ws[4] = {w2,w4,w6,w8};
  const float* wB = ws[l2i] + ((ab*2+q)*8 + c)*d2;
  float s = 0.f;
  if (d1) {   // FormA
    const float* wA = ws[l1i] + ((ab*2+p)*8 + c)*d1;
    for (int a=0;a<d1;a++){
      float t = 0.f;
      for (int j=0;j<d2;j++) t += wB[j]*R[a*d2+j];
      s += wA[a]*t;
    }
  } else {    // FormB
    for (int j=0;j<d2;j++) s += wB[j]*R[j];
  }
  V[abc*UVS + dst] = s;
}

// ---------------- fused phase 1+2, G=2 voxels: one (t,k1) item -> 8 (or 4) U values ----------------
template<int D1>
__device__ __forceinline__ void u_itemA(const float* __restrict__ Lp, const float* xb,
    float* Ush, int dst, int dstr, int xo1, int xo2, int d2)
{
  float x0r[2*D1], x1r[2*D1];
  #pragma unroll
  for (int j=0;j<2*D1;j++){ x0r[j] = xb[xo1+j]; x1r[j] = xb[XBS+xo1+j]; }
  float a00=0.f,a01=0.f,a10=0.f,a11=0.f;
  float b00=0.f,b01=0.f,b10=0.f,b11=0.f;
  for (int b=0;b<d2;b++){
    float i00=0.f, i01=0.f, i10=0.f, i11=0.f;     // i{voxel}{p}
    const float* Lb = Lp + b*D1;                   // contiguous slab: 8 FMAs per CG load
    #pragma unroll
    for (int j=0;j<D1;j++){
      const float lv=Lb[j];
      i00+=lv*x0r[j]; i01+=lv*x0r[D1+j];
      i10+=lv*x1r[j]; i11+=lv*x1r[D1+j];
    }
    const float q00=xb[xo2+b],     q01=xb[xo2+d2+b];
    const float q10=xb[XBS+xo2+b], q11=xb[XBS+xo2+d2+b];
    a00+=q00*i00; a01+=q01*i00; a10+=q00*i01; a11+=q01*i01;
    b00+=q10*i10; b01+=q11*i10; b10+=q10*i11; b11+=q11*i11;
  }
  Ush[dst]=a00; Ush[dst+dstr]=a01; Ush[dst+2*dstr]=a10; Ush[dst+3*dstr]=a11;
  Ush[UVS+dst]=b00; Ush[UVS+dst+dstr]=b01; Ush[UVS+dst+2*dstr]=b10; Ush[UVS+dst+3*dstr]=b11;
}

__device__ __forceinline__ void u_item(const int4 w, const float* __restrict__ cg,
                                       const float* xb, float* Ush)
{
  const float* Lp = cg + w.x;
  const int dst = w.y & 0xFFFF, dstr = ((unsigned)w.y) >> 16;
  const int xo1 = w.z & 0xFF, xo2 = (w.z>>8)&0xFF;
  const int d1 = (w.z>>16)&0x3F, d2 = ((unsigned)w.z)>>22;
  if (d1 == 0){                         // FormB: U'[q][k1] = sum_b L[k1,b]*x2[q,b]
    float a0=0.f, a1=0.f, b0=0.f, b1=0.f;
    for (int b=0;b<d2;b++){
      const float lv=Lp[b];
      a0+=lv*xb[xo2+b];     a1+=lv*xb[xo2+d2+b];
      b0+=lv*xb[XBS+xo2+b]; b1+=lv*xb[XBS+xo2+d2+b];
    }
    Ush[dst]=a0; Ush[dst+dstr]=a1;
    Ush[UVS+dst]=b0; Ush[UVS+dst+dstr]=b1;
    return;
  }
  switch(d1){
    case 5:  u_itemA<5>(Lp,xb,Ush,dst,dstr,xo1,xo2,d2); break;
    case 9:  u_itemA<9>(Lp,xb,Ush,dst,dstr,xo1,xo2,d2); break;
    case 13: u_itemA<13>(Lp,xb,Ush,dst,dstr,xo1,xo2,d2); break;
    default: u_itemA<17>(Lp,xb,Ush,dst,dstr,xo1,xo2,d2); break;
  }
}

// ---------------- phase-3 column worker (one (c, l, k2) column) -> z into LDS ----------------
template<int LI>
__device__ __forceinline__ float col_work(int k2, float rh0c, float c000,
    const float* __restrict__ Vc, const float* Ush,
    float* zsh, int zb)
{
  constexpr int d   = (LI==0)?1:(LI==1)?5:(LI==2)?9:(LI==3)?13:17;
  constexpr int np4 = (d+3)/4;
  float4 za[np4];
  #pragma unroll
  for (int i=0;i<np4;i++) za[i] = make_float4(0.f,0.f,0.f,0.f);
  #pragma unroll
  for (int t=T0G[LI]; t<T0G[LI+1]; t++){
    const auto &m = META.t[t];
    if (m.form==2){
      za[0].x += rh0c*rh0c*c000;
    } else {
      const int npr = (m.form==0)?4:2;
      #pragma unroll
      for (int pr=0;pr<npr;pr++){
        float v = Vc[m.uv + pr*m.dp4 + k2];
        if (m.form==1) v *= rh0c;
        const float4* Up = reinterpret_cast<const float4*>(Ush + m.uv + pr*m.dp4);
        #pragma unroll
        for (int rr=0;rr<np4;rr++){
          float4 u = Up[rr];           // wave-uniform LDS broadcast
          za[rr].x += u.x*v; za[rr].y += u.y*v; za[rr].z += u.z*v; za[rr].w += u.w*v;
        }
      }
    }
  }
  float s = 0.f;
  #pragma unroll
  for (int rr=0;rr<np4;rr++){
    const float vals[4] = {za[rr].x, za[rr].y, za[rr].z, za[rr].w};
    #pragma unroll
    for (int e=0;e<4;e++){
      const int k1 = 4*rr+e;
      if (k1 < d){
        zsh[zb + k1*d + k2] = vals[e];   // LDS scatter; global store is phase 3b
        s += vals[e]*vals[e];
      }
    }
  }
  return s;
}

// ---------------- kernel 2: main, one block per 2 voxels ----------------
__global__ __launch_bounds__(WGB,4) void s2_main(
    const float* __restrict__ x0, const float* __restrict__ x2, const float* __restrict__ x4,
    const float* __restrict__ x6, const float* __restrict__ x8,
    const float* __restrict__ w0, const float* __restrict__ bias,
    const float* __restrict__ cg, const int4* __restrict__ wiU,
    const float* __restrict__ V, float* __restrict__ out, float c000)
{
  __shared__ alignas(16) float SH[ZTOT + 2*UVS];   // [z | U(v0) | U(v1)]
  __shared__ float xb[2*XBS];
  __shared__ float rh0s[16];
  __shared__ float fpart[360];
  const int tid = threadIdx.x;
  const int bid = blockIdx.x;
  const int ab  = bid >> 9;            // vox = bid*2+v; both voxels share ab
  float* Ush = SH + ZTOT;

  // ---- phase 0: stage x for 2 voxels (half-block each), compute rh0 ----
  {
    const int v  = tid >> 7;           // 0 or 1
    const int t2 = tid & 127;
    const int vox = bid*2 + v;
    float* xv = xb + v*XBS;
    if (t2 < 5)        xv[t2]           = x0[vox*5  + t2];
    else if (t2 < 15)  xv[8  + (t2-5)]  = x2[vox*10 + (t2-5)];
    else if (t2 < 33)  xv[18 + (t2-15)] = x4[vox*18 + (t2-15)];
    else if (t2 < 59)  xv[36 + (t2-33)] = x6[vox*26 + (t2-33)];
    else if (t2 < 93)  xv[62 + (t2-59)] = x8[vox*34 + (t2-59)];
    else if (t2 >= 96 && t2 < 104) {
      const int c = t2 - 96;
      float s = bias[ab*8 + c];
      for (int i=0;i<5;i++) s += x0[vox*5+i] * w0[(ab*5+i)*8 + c];
      rh0s[v*8 + c] = s;
    }
  }
  __syncthreads();

  // ---- phase 1+2 fused (both voxels per CG load): items snake-balanced ----
  u_item(wiU[tid], cg, xb, Ush);
  {
    const int r = NUC-1-tid;
    if (r >= WGB) u_item(wiU[r], cg, xb, Ush);
  }
  __syncthreads();

  // ---- phases 3/3b/4 per voxel, z buffer reused ----
  const float* Vab = V + (ab*8)*UVS;
  #pragma unroll
  for (int v=0; v<2; v++){
    const int bid2 = bid*2 + v;
    const float* Uv = Ush + v*UVS;
    for (int col=tid; col<360; col+=WGB){
      int li, c, k2;
      if (col < 136)      { li=4; c = col/17;            k2 = col - c*17; }
      else if (col < 240) { const int r=col-136; li=3; c=r/13; k2=r-c*13; }
      else if (col < 312) { const int r=col-240; li=2; c=r/9;  k2=r-c*9;  }
      else if (col < 352) { const int r=col-312; li=1; c=r/5;  k2=r-c*5;  }
      else                { li=0; c=col-352; k2=0; }
      const int d = DL[li];
      const float rh0c = rh0s[v*8 + c];
      const float* Vc = Vab + c*UVS;
      const int zb = ZB[li] + c*d*d;
      float s;
      switch(li){
        case 4:  s = col_work<4>(k2, rh0c, c000, Vc, Uv, SH, zb); break;
        case 3:  s = col_work<3>(k2, rh0c, c000, Vc, Uv, SH, zb); break;
        case 2:  s = col_work<2>(k2, rh0c, c000, Vc, Uv, SH, zb); break;
        case 1:  s = col_work<1>(k2, rh0c, c000, Vc, Uv, SH, zb); break;
        default: s = col_work<0>(k2, rh0c, c000, Vc, Uv, SH, zb); break;
      }
      fpart[col] = s;
    }
    __syncthreads();

    // phase 3b: coalesced vf4 copy LDS z -> global rh_n
    for (int i4 = tid; i4 < 1130; i4 += WGB){
      int li;
      if      (i4 < C4[1]) li = 0;
      else if (i4 < C4[2]) li = 1;
      else if (i4 < C4[3]) li = 2;
      else if (i4 < C4[4]) li = 3;
      else                 li = 4;
      const int r4 = i4 - C4[li];
      const vf4 zv = *reinterpret_cast<const vf4*>(SH + ZB[li] + 4*r4);
      __builtin_nontemporal_store(zv, reinterpret_cast<vf4*>(out + RHNB[li] + bid2*LEN5[li] + 4*r4));
    }

    // phase 4: feats reduce: n_l * sum z^2, layout (A,B, 5*N*C)
    if (tid < 40){
      const int li = tid >> 3, c = tid & 7;
      const int d = DL[li];
      float s = 0.f;
      for (int k2=0;k2<d;k2++) s += fpart[CBASE[li] + c*d + k2];
      const double nl_d = 8.0*3.14159265358979323846*3.14159265358979323846/(double)(2*(2*li)+1);
      const int n = bid2 & 1023;
      __builtin_nontemporal_store((float)nl_d * s, out + ab*40960 + li*8192 + n*8 + c);
    }
    if (v==0) __syncthreads();   // protect z/fpart before next voxel overwrites
  }
}

// ---------------- host: numpy MT19937 + legacy gauss, tables + CG upload at dlopen ----------------
namespace {

struct MTRng {
  uint32_t mt[624]; int mti;
  bool has_g; double g;
  void seed(uint32_t s){
    for (int pos=0; pos<624; pos++){ mt[pos]=s; s = 1812433253u*(s^(s>>30)) + (uint32_t)pos + 1u; }
    mti = 624; has_g=false; g=0.0;
  }
  uint32_t next32(){
    if (mti >= 624){
      for (int i=0;i<624;i++){
        uint32_t y = (mt[i]&0x80000000u) | (mt[(i+1)%624]&0x7fffffffu);
        mt[i] = mt[(i+397)%624] ^ (y>>1) ^ ((y&1u) ? 0x9908b0dfu : 0u);
      }
      mti = 0;
    }
    uint32_t y = mt[mti++];
    y ^= y>>11; y ^= (y<<7)&0x9d2c5680u; y ^= (y<<15)&0xefc60000u; y ^= y>>18;
    return y;
  }
  double rk_double(){
    uint32_t a = next32()>>5, b = next32()>>6;
    return (a*67108864.0 + b)/9007199254740992.0;
  }
  double gauss(){
    if (has_g){ has_g=false; return g; }
    double f,x1,x2,r2;
    do {
      x1 = 2.0*rk_double()-1.0;
      x2 = 2.0*rk_double()-1.0;
      r2 = x1*x1 + x2*x2;
    } while (r2 >= 1.0 || r2 == 0.0);
    f = std::sqrt(-2.0*std::log(r2)/r2);
    g = f*x1; has_g = true;
    return f*x2;
  }
};

constexpr int XOFS_H[5] = {0,8,18,36,62};

struct DeviceSetup {
  float* d_cg  = nullptr;   // [CG_R | CG_L]  (2*CG_TOTAL floats)
  float* d_v   = nullptr;   // 32 * UVS floats, rewritten by s2_prep every launch
  int4*  d_wiU = nullptr;
  int2*  d_wiv = nullptr;
  float  c000  = 0.f;
  DeviceSetup(){
    // CG tables, bit-faithful numpy RandomState(42)
    std::vector<float> h(2*CG_TOTAL);
    MTRng r; r.seed(42u);
    for (int i=0;i<2*CG_TOTAL;i++) h[i] = (float)(r.gauss()*0.1);
    c000 = h[META_H.t[0].cgL] * h[META_H.t[0].cgR];

    // fused U work items: one per (t,k1)
    std::vector<std::pair<int,int4>> tmp;
    for (int t=0;t<META_H.nT;t++){
      const TripleMeta &m = META_H.t[t];
      if (m.form==0){
        const int xo1 = XOFS_H[m.l1>>1], xo2 = XOFS_H[m.l2>>1];
        for (int k1=0;k1<m.d;k1++){
          int4 e;
          e.x = m.cgL + k1*m.d1*m.d2;
          e.y = (m.uv + k1) | (m.dp4<<16);
          e.z = xo1 | (xo2<<8) | (m.d1<<16) | (m.d2<<22);
          e.w = 0;
          tmp.push_back({m.d2*(2*m.d1+4), e});
        }
      } else if (m.form==1){
        const int xo2 = XOFS_H[m.l2>>1];
        for (int k1=0;k1<m.d;k1++){
          int4 e;
          e.x = m.cgL + k1*m.d2;
          e.y = (m.uv + k1) | (m.dp4<<16);
          e.z = (xo2<<8) | (0<<16) | (m.d2<<22);
          e.w = 0;
          tmp.push_back({2*m.d2, e});
        }
      }
    }
    if ((int)tmp.size() != NUC) std::abort();
    std::stable_sort(tmp.begin(), tmp.end(),
                     [](const std::pair<int,int4>&a, const std::pair<int,int4>&b){
                       return a.first > b.first; });
    std::vector<int4> wiU(NUC);
    for (int i=0;i<NUC;i++) wiU[i] = tmp[i].second;

    // V work items (per (ab,c); abc decoded in-kernel)
    std::vector<int2> wiv;
    for (int t=0;t<META_H.nT;t++){
      const TripleMeta &m = META_H.t[t];
      if (m.form==0){
        const int l1i = (m.l1>>1)-1, l2i = (m.l2>>1)-1;
        for (int pq=0;pq<4;pq++){
          const int p = pq>>1, q = pq&1;
          for (int k2=0;k2<m.d;k2++){
            int2 e;
            e.x = m.cgR + k2*m.d1*m.d2;
            e.y = (m.uv + pq*m.dp4 + k2) | (p<<12) | (q<<13) | (l1i<<14) | (l2i<<16)
                | (m.d1<<18) | (m.d2<<23);
            wiv.push_back(e);
          }
        }
      } else if (m.form==1){
        const int l2i = (m.l2>>1)-1;
        for (int q=0;q<2;q++){
          for (int k2=0;k2<m.d;k2++){
            int2 e;
            e.x = m.cgR + k2*m.d2;
            e.y = (m.uv + q*m.dp4 + k2) | (q<<13) | (l2i<<16) | (0<<18) | (m.d2<<23);
            wiv.push_back(e);
          }
        }
      }
    }
    if ((int)wiv.size() != NVC) std::abort();

    (void)hipMalloc((void**)&d_cg,  sizeof(float)*2*CG_TOTAL);
    (void)hipMalloc((void**)&d_v,   sizeof(float)*32*UVS);
    (void)hipMalloc((void**)&d_wiU, sizeof(int4)*NUC);
    (void)hipMalloc((void**)&d_wiv, sizeof(int2)*NVC);
    (void)hipMemcpy(d_cg,  h.data(),    sizeof(float)*2*CG_TOTAL, hipMemcpyHostToDevice);
    (void)hipMemcpy(d_wiU, wiU.data(),  sizeof(int4)*NUC,  hipMemcpyHostToDevice);
    (void)hipMemcpy(d_wiv, wiv.data(),  sizeof(int2)*NVC,  hipMemcpyHostToDevice);
  }
};
DeviceSetup g_dev;   // static init at dlopen: pure-CPU RNG + one-time uploads (outside graph capture)

} // namespace

extern "C" void kernel_launch(void* const* d_in, const int* in_sizes, int n_in,
                              void* d_out, int out_size, void* d_ws, size_t ws_size,
                              hipStream_t stream)
{
  (void)in_sizes; (void)n_in; (void)d_ws; (void)ws_size; (void)out_size;
  const float* x0   = (const float*)d_in[0];
  const float* w0   = (const float*)d_in[1];
  const float* x2   = (const float*)d_in[2];
  const float* w2   = (const float*)d_in[3];
  const float* x4   = (const float*)d_in[4];
  const float* w4   = (const float*)d_in[5];
  const float* x6   = (const float*)d_in[6];
  const float* w6   = (const float*)d_in[7];
  const float* x8   = (const float*)d_in[8];
  const float* w8   = (const float*)d_in[9];
  const float* bias = (const float*)d_in[10];
  float* out = (float*)d_out;

  const int prep_blocks = (32*NVC + WGB - 1) / WGB;
  s2_prep<<<dim3(prep_blocks), dim3(WGB), 0, stream>>>(w2,w4,w6,w8, g_dev.d_cg, g_dev.d_wiv, g_dev.d_v);
  s2_main<<<dim3(2048), dim3(WGB), 0, stream>>>(x0,x2,x4,x6,x8, w0, bias,
                                                g_dev.d_cg, g_dev.d_wiU,
                                                g_dev.d_v, out, g_dev.c000);
}

// Round 8
// 249.866 us; speedup vs baseline: 1.6262x; 1.1765x over previous
//
#include <hip/hip_runtime.h>
#include <cmath>
#include <cstdint>
#include <vector>
#include <cstdlib>
#include <algorithm>

#define WGB 256

typedef float vf4 __attribute__((ext_vector_type(4)));   // native vector: OK for nontemporal builtins

// ---------------- constexpr problem metadata (evaluated identically host+device) ----------------
struct TripleMeta { int l,l1,l2,d,d1,d2,form,dp4,cgR,cgL,uv; };
struct AllMeta { TripleMeta t[48]; int nT, cgTotal, uvTotal; };

constexpr AllMeta build_meta() {
  AllMeta M{};
  const int LSl[5] = {0,2,4,6,8};
  int k=0, cg=0;
  for (int a=0;a<5;a++){ const int l=LSl[a];
    for (int b=0;b<5;b++){ const int l1=LSl[b];
      for (int l2=l1;l2<=8;l2+=2){
        if (!((l2-l1)<=l && l<=(l1+l2))) continue;
        TripleMeta m{};
        m.l=l; m.l1=l1; m.l2=l2;
        m.d=2*l+1; m.d1=2*l1+1; m.d2=2*l2+1;
        m.form = (l1==0) ? ((l2==0)?2:1) : 0;   // 0=A (l1>0), 1=B (l1==0,l2>0), 2=D (0,0,0)
        m.dp4 = ((m.d+3)/4)*4;
        m.cgR = cg; cg += m.d*m.d1*m.d2;
        M.t[k] = m; k++;
      } } }
  M.nT=k; M.cgTotal=cg;
  int cgl=cg;
  for (int i=0;i<k;i++){ M.t[i].cgL=cgl; cgl += M.t[i].d*M.t[i].d1*M.t[i].d2; }
  int uv=0;
  for (int i=0;i<k;i++){
    if (M.t[i].form==0){ M.t[i].uv=uv; uv += 4*M.t[i].dp4; }
    else if (M.t[i].form==1){ M.t[i].uv=uv; uv += 2*M.t[i].dp4; }
  }
  M.uvTotal=uv;
  return M;
}

constexpr AllMeta META_H = build_meta();            // host view
static_assert(META_H.nT==42, "nT");
static_assert(META_H.cgTotal==52334, "cgTotal");
static_assert(META_H.uvTotal==2048, "uvTotal");

__device__ constexpr AllMeta META = build_meta();   // device view (identical values)

constexpr int CG_TOTAL  = 52334;
constexpr int UVS       = 2048;      // U/V slot-table stride (floats)
constexpr int ZTOT      = 4520;      // z-buffer floats in LDS (8*d^2 summed)
constexpr int NUC       = 417;       // fused U work items (373 FormA + 44 FormB)
constexpr int XBS       = 104;       // per-voxel xb stride in LDS

__device__ constexpr int DL[5]     = {1,5,9,13,17};
__device__ constexpr int T0G[6]    = {0,5,13,23,33,42};       // triple ranges per output-l group
__device__ constexpr int RHNB[5]   = {163840,196608,1015808,3670016,9207808}; // rh_n out offsets
__device__ constexpr int CBASE[5]  = {352,312,240,136,0};     // phase-3 column base per li
// z-buffer: per-li base, 8*d^2 each; all %4==0 for float4 copy
__device__ constexpr int ZB[5]     = {0,8,208,856,2208};
__device__ constexpr int LEN5[5]   = {8,200,648,1352,2312};
__device__ constexpr int C4[6]     = {0,2,52,214,552,1130};   // cumulative float4 counts

// ---------------- kernel 1: V table — one block per (triple, abc), CG slab staged in LDS ----------------
// V_{t,p,q}[k2] = sum_a wA[p,a] * sum_j wB[q,j] * R_t[k2,a,j]
__global__ __launch_bounds__(128) void s2_prep(
    const float* __restrict__ w2, const float* __restrict__ w4,
    const float* __restrict__ w6, const float* __restrict__ w8,
    const float* __restrict__ cg, float* __restrict__ V)
{
  __shared__ float Rs[4928];           // max d*d1*d2 = 17*17*17 = 4913
  const int bid = blockIdx.x;
  const int t   = bid >> 5;
  const int abc = bid & 31;
  const auto &m = META.t[t];
  if (m.form == 2) return;             // (0,0,0) handled analytically in s2_main
  const int ab = abc >> 3, c = abc & 7;
  const int sz = m.d * m.d1 * m.d2;
  for (int i = threadIdx.x; i < sz; i += 128) Rs[i] = cg[m.cgR + i];   // coalesced
  __syncthreads();
  const float* ws[4] = {w2,w4,w6,w8};
  const int nout = (m.form==0 ? 4 : 2) * m.d;
  if ((int)threadIdx.x < nout){
    const int pq = threadIdx.x / m.d;
    const int k2 = threadIdx.x - pq*m.d;
    float s = 0.f;
    if (m.form==0){
      const int p = pq>>1, q = pq&1;
      const float* wA = ws[(m.l1>>1)-1] + ((ab*2+p)*8 + c)*m.d1;   // wave-uniform-ish broadcast
      const float* wB = ws[(m.l2>>1)-1] + ((ab*2+q)*8 + c)*m.d2;
      const float* Rk = Rs + k2*m.d1*m.d2;
      for (int a=0;a<m.d1;a++){
        float t2 = 0.f;
        for (int j=0;j<m.d2;j++) t2 += wB[j]*Rk[a*m.d2+j];
        s += wA[a]*t2;
      }
    } else {
      const float* wB = ws[(m.l2>>1)-1] + ((ab*2+pq)*8 + c)*m.d2;
      const float* Rk = Rs + k2*m.d2;   // d1==1
      for (int j=0;j<m.d2;j++) s += wB[j]*Rk[j];
    }
    V[abc*UVS + m.uv + pq*m.dp4 + k2] = s;
  }
}

// ---------------- fused phase 1+2, G=2 voxels: one (t,k1) item -> 8 (or 4) U values ----------------
template<int D1>
__device__ __forceinline__ void u_itemA(const float* __restrict__ Lp, const float* xb,
    float* Ush, int dst, int dstr, int xo1, int xo2, int d2)
{
  float x0r[2*D1], x1r[2*D1];
  #pragma unroll
  for (int j=0;j<2*D1;j++){ x0r[j] = xb[xo1+j]; x1r[j] = xb[XBS+xo1+j]; }
  float a00=0.f,a01=0.f,a10=0.f,a11=0.f;
  float b00=0.f,b01=0.f,b10=0.f,b11=0.f;
  for (int b=0;b<d2;b++){
    float i00=0.f, i01=0.f, i10=0.f, i11=0.f;     // i{voxel}{p}
    const float* Lb = Lp + b*D1;                   // contiguous slab: 8 FMAs per CG load
    #pragma unroll
    for (int j=0;j<D1;j++){
      const float lv=Lb[j];
      i00+=lv*x0r[j]; i01+=lv*x0r[D1+j];
      i10+=lv*x1r[j]; i11+=lv*x1r[D1+j];
    }
    const float q00=xb[xo2+b],     q01=xb[xo2+d2+b];
    const float q10=xb[XBS+xo2+b], q11=xb[XBS+xo2+d2+b];
    a00+=q00*i00; a01+=q01*i00; a10+=q00*i01; a11+=q01*i01;
    b00+=q10*i10; b01+=q11*i10; b10+=q10*i11; b11+=q11*i11;
  }
  Ush[dst]=a00; Ush[dst+dstr]=a01; Ush[dst+2*dstr]=a10; Ush[dst+3*dstr]=a11;
  Ush[UVS+dst]=b00; Ush[UVS+dst+dstr]=b01; Ush[UVS+dst+2*dstr]=b10; Ush[UVS+dst+3*dstr]=b11;
}

__device__ __forceinline__ void u_item(const int4 w, const float* __restrict__ cg,
                                       const float* xb, float* Ush)
{
  const float* Lp = cg + w.x;
  const int dst = w.y & 0xFFFF, dstr = ((unsigned)w.y) >> 16;
  const int xo1 = w.z & 0xFF, xo2 = (w.z>>8)&0xFF;
  const int d1 = (w.z>>16)&0x3F, d2 = ((unsigned)w.z)>>22;
  if (d1 == 0){                         // FormB: U'[q][k1] = sum_b L[k1,b]*x2[q,b]
    float a0=0.f, a1=0.f, b0=0.f, b1=0.f;
    for (int b=0;b<d2;b++){
      const float lv=Lp[b];
      a0+=lv*xb[xo2+b];     a1+=lv*xb[xo2+d2+b];
      b0+=lv*xb[XBS+xo2+b]; b1+=lv*xb[XBS+xo2+d2+b];
    }
    Ush[dst]=a0; Ush[dst+dstr]=a1;
    Ush[UVS+dst]=b0; Ush[UVS+dst+dstr]=b1;
    return;
  }
  switch(d1){
    case 5:  u_itemA<5>(Lp,xb,Ush,dst,dstr,xo1,xo2,d2); break;
    case 9:  u_itemA<9>(Lp,xb,Ush,dst,dstr,xo1,xo2,d2); break;
    case 13: u_itemA<13>(Lp,xb,Ush,dst,dstr,xo1,xo2,d2); break;
    default: u_itemA<17>(Lp,xb,Ush,dst,dstr,xo1,xo2,d2); break;
  }
}

// ---------------- phase-3 column worker (one (c, l, k2) column) -> z into LDS ----------------
template<int LI>
__device__ __forceinline__ float col_work(int k2, float rh0c, float c000,
    const float* __restrict__ Vc, const float* Ush,
    float* zsh, int zb)
{
  constexpr int d   = (LI==0)?1:(LI==1)?5:(LI==2)?9:(LI==3)?13:17;
  constexpr int np4 = (d+3)/4;
  float4 za[np4];
  #pragma unroll
  for (int i=0;i<np4;i++) za[i] = make_float4(0.f,0.f,0.f,0.f);
  #pragma unroll
  for (int t=T0G[LI]; t<T0G[LI+1]; t++){
    const auto &m = META.t[t];
    if (m.form==2){
      za[0].x += rh0c*rh0c*c000;
    } else {
      const int npr = (m.form==0)?4:2;
      #pragma unroll
      for (int pr=0;pr<npr;pr++){
        float v = Vc[m.uv + pr*m.dp4 + k2];
        if (m.form==1) v *= rh0c;
        const float4* Up = reinterpret_cast<const float4*>(Ush + m.uv + pr*m.dp4);
        #pragma unroll
        for (int rr=0;rr<np4;rr++){
          float4 u = Up[rr];           // wave-uniform LDS broadcast
          za[rr].x += u.x*v; za[rr].y += u.y*v; za[rr].z += u.z*v; za[rr].w += u.w*v;
        }
      }
    }
  }
  float s = 0.f;
  #pragma unroll
  for (int rr=0;rr<np4;rr++){
    const float vals[4] = {za[rr].x, za[rr].y, za[rr].z, za[rr].w};
    #pragma unroll
    for (int e=0;e<4;e++){
      const int k1 = 4*rr+e;
      if (k1 < d){
        zsh[zb + k1*d + k2] = vals[e];   // LDS scatter; global store is phase 3b
        s += vals[e]*vals[e];
      }
    }
  }
  return s;
}

// ---------------- kernel 2: main, one block per 2 voxels ----------------
__global__ __launch_bounds__(WGB,4) void s2_main(
    const float* __restrict__ x0, const float* __restrict__ x2, const float* __restrict__ x4,
    const float* __restrict__ x6, const float* __restrict__ x8,
    const float* __restrict__ w0, const float* __restrict__ bias,
    const float* __restrict__ cg, const int4* __restrict__ wiU,
    const float* __restrict__ V, float* __restrict__ out, float c000)
{
  __shared__ alignas(16) float SH[ZTOT + 2*UVS];   // [z | U(v0) | U(v1)]
  __shared__ float xb[2*XBS];
  __shared__ float rh0s[16];
  __shared__ float fpart[360];
  const int tid = threadIdx.x;
  const int bid = blockIdx.x;
  const int ab  = bid >> 9;            // vox = bid*2+v; both voxels share ab
  float* Ush = SH + ZTOT;

  // ---- phase 0: stage x for 2 voxels (half-block each), compute rh0 ----
  {
    const int v  = tid >> 7;           // 0 or 1
    const int t2 = tid & 127;
    const int vox = bid*2 + v;
    float* xv = xb + v*XBS;
    if (t2 < 5)        xv[t2]           = x0[vox*5  + t2];
    else if (t2 < 15)  xv[8  + (t2-5)]  = x2[vox*10 + (t2-5)];
    else if (t2 < 33)  xv[18 + (t2-15)] = x4[vox*18 + (t2-15)];
    else if (t2 < 59)  xv[36 + (t2-33)] = x6[vox*26 + (t2-33)];
    else if (t2 < 93)  xv[62 + (t2-59)] = x8[vox*34 + (t2-59)];
    else if (t2 >= 96 && t2 < 104) {
      const int c = t2 - 96;
      float s = bias[ab*8 + c];
      for (int i=0;i<5;i++) s += x0[vox*5+i] * w0[(ab*5+i)*8 + c];
      rh0s[v*8 + c] = s;
    }
  }
  __syncthreads();

  // ---- phase 1+2 fused (both voxels per CG load): items snake-balanced ----
  u_item(wiU[tid], cg, xb, Ush);
  {
    const int r = NUC-1-tid;
    if (r >= WGB) u_item(wiU[r], cg, xb, Ush);
  }
  __syncthreads();

  // ---- phases 3/3b/4 per voxel, z buffer reused ----
  const float* Vab = V + (ab*8)*UVS;
  #pragma unroll
  for (int v=0; v<2; v++){
    const int bid2 = bid*2 + v;
    const float* Uv = Ush + v*UVS;
    for (int col=tid; col<360; col+=WGB){
      int li, c, k2;
      if (col < 136)      { li=4; c = col/17;            k2 = col - c*17; }
      else if (col < 240) { const int r=col-136; li=3; c=r/13; k2=r-c*13; }
      else if (col < 312) { const int r=col-240; li=2; c=r/9;  k2=r-c*9;  }
      else if (col < 352) { const int r=col-312; li=1; c=r/5;  k2=r-c*5;  }
      else                { li=0; c=col-352; k2=0; }
      const int d = DL[li];
      const float rh0c = rh0s[v*8 + c];
      const float* Vc = Vab + c*UVS;
      const int zb = ZB[li] + c*d*d;
      float s;
      switch(li){
        case 4:  s = col_work<4>(k2, rh0c, c000, Vc, Uv, SH, zb); break;
        case 3:  s = col_work<3>(k2, rh0c, c000, Vc, Uv, SH, zb); break;
        case 2:  s = col_work<2>(k2, rh0c, c000, Vc, Uv, SH, zb); break;
        case 1:  s = col_work<1>(k2, rh0c, c000, Vc, Uv, SH, zb); break;
        default: s = col_work<0>(k2, rh0c, c000, Vc, Uv, SH, zb); break;
      }
      fpart[col] = s;
    }
    __syncthreads();

    // phase 3b: coalesced vf4 copy LDS z -> global rh_n
    for (int i4 = tid; i4 < 1130; i4 += WGB){
      int li;
      if      (i4 < C4[1]) li = 0;
      else if (i4 < C4[2]) li = 1;
      else if (i4 < C4[3]) li = 2;
      else if (i4 < C4[4]) li = 3;
      else                 li = 4;
      const int r4 = i4 - C4[li];
      const vf4 zv = *reinterpret_cast<const vf4*>(SH + ZB[li] + 4*r4);
      __builtin_nontemporal_store(zv, reinterpret_cast<vf4*>(out + RHNB[li] + bid2*LEN5[li] + 4*r4));
    }

    // phase 4: feats reduce: n_l * sum z^2, layout (A,B, 5*N*C)
    if (tid < 40){
      const int li = tid >> 3, c = tid & 7;
      const int d = DL[li];
      float s = 0.f;
      for (int k2=0;k2<d;k2++) s += fpart[CBASE[li] + c*d + k2];
      const double nl_d = 8.0*3.14159265358979323846*3.14159265358979323846/(double)(2*(2*li)+1);
      const int n = bid2 & 1023;
      __builtin_nontemporal_store((float)nl_d * s, out + ab*40960 + li*8192 + n*8 + c);
    }
    if (v==0) __syncthreads();   // protect z/fpart before next voxel overwrites
  }
}

// ---------------- host: numpy MT19937 + legacy gauss, tables + CG upload at dlopen ----------------
namespace {

struct MTRng {
  uint32_t mt[624]; int mti;
  bool has_g; double g;
  void seed(uint32_t s){
    for (int pos=0; pos<624; pos++){ mt[pos]=s; s = 1812433253u*(s^(s>>30)) + (uint32_t)pos + 1u; }
    mti = 624; has_g=false; g=0.0;
  }
  uint32_t next32(){
    if (mti >= 624){
      for (int i=0;i<624;i++){
        uint32_t y = (mt[i]&0x80000000u) | (mt[(i+1)%624]&0x7fffffffu);
        mt[i] = mt[(i+397)%624] ^ (y>>1) ^ ((y&1u) ? 0x9908b0dfu : 0u);
      }
      mti = 0;
    }
    uint32_t y = mt[mti++];
    y ^= y>>11; y ^= (y<<7)&0x9d2c5680u; y ^= (y<<15)&0xefc60000u; y ^= y>>18;
    return y;
  }
  double rk_double(){
    uint32_t a = next32()>>5, b = next32()>>6;
    return (a*67108864.0 + b)/9007199254740992.0;
  }
  double gauss(){
    if (has_g){ has_g=false; return g; }
    double f,x1,x2,r2;
    do {
      x1 = 2.0*rk_double()-1.0;
      x2 = 2.0*rk_double()-1.0;
      r2 = x1*x1 + x2*x2;
    } while (r2 >= 1.0 || r2 == 0.0);
    f = std::sqrt(-2.0*std::log(r2)/r2);
    g = f*x1; has_g = true;
    return f*x2;
  }
};

constexpr int XOFS_H[5] = {0,8,18,36,62};

struct DeviceSetup {
  float* d_cg  = nullptr;   // [CG_R | CG_L]  (2*CG_TOTAL floats)
  float* d_v   = nullptr;   // 32 * UVS floats, rewritten by s2_prep every launch
  int4*  d_wiU = nullptr;
  float  c000  = 0.f;
  DeviceSetup(){
    // CG tables, bit-faithful numpy RandomState(42)
    std::vector<float> h(2*CG_TOTAL);
    MTRng r; r.seed(42u);
    for (int i=0;i<2*CG_TOTAL;i++) h[i] = (float)(r.gauss()*0.1);
    c000 = h[META_H.t[0].cgL] * h[META_H.t[0].cgR];

    // fused U work items: one per (t,k1)
    std::vector<std::pair<int,int4>> tmp;
    for (int t=0;t<META_H.nT;t++){
      const TripleMeta &m = META_H.t[t];
      if (m.form==0){
        const int xo1 = XOFS_H[m.l1>>1], xo2 = XOFS_H[m.l2>>1];
        for (int k1=0;k1<m.d;k1++){
          int4 e;
          e.x = m.cgL + k1*m.d1*m.d2;
          e.y = (m.uv + k1) | (m.dp4<<16);
          e.z = xo1 | (xo2<<8) | (m.d1<<16) | (m.d2<<22);
          e.w = 0;
          tmp.push_back({m.d2*(2*m.d1+4), e});
        }
      } else if (m.form==1){
        const int xo2 = XOFS_H[m.l2>>1];
        for (int k1=0;k1<m.d;k1++){
          int4 e;
          e.x = m.cgL + k1*m.d2;
          e.y = (m.uv + k1) | (m.dp4<<16);
          e.z = (xo2<<8) | (0<<16) | (m.d2<<22);
          e.w = 0;
          tmp.push_back({2*m.d2, e});
        }
      }
    }
    if ((int)tmp.size() != NUC) std::abort();
    std::stable_sort(tmp.begin(), tmp.end(),
                     [](const std::pair<int,int4>&a, const std::pair<int,int4>&b){
                       return a.first > b.first; });
    std::vector<int4> wiU(NUC);
    for (int i=0;i<NUC;i++) wiU[i] = tmp[i].second;

    (void)hipMalloc((void**)&d_cg,  sizeof(float)*2*CG_TOTAL);
    (void)hipMalloc((void**)&d_v,   sizeof(float)*32*UVS);
    (void)hipMalloc((void**)&d_wiU, sizeof(int4)*NUC);
    (void)hipMemcpy(d_cg,  h.data(),    sizeof(float)*2*CG_TOTAL, hipMemcpyHostToDevice);
    (void)hipMemcpy(d_wiU, wiU.data(),  sizeof(int4)*NUC,  hipMemcpyHostToDevice);
  }
};
DeviceSetup g_dev;   // static init at dlopen: pure-CPU RNG + one-time uploads (outside graph capture)

} // namespace

extern "C" void kernel_launch(void* const* d_in, const int* in_sizes, int n_in,
                              void* d_out, int out_size, void* d_ws, size_t ws_size,
                              hipStream_t stream)
{
  (void)in_sizes; (void)n_in; (void)d_ws; (void)ws_size; (void)out_size;
  const float* x0   = (const float*)d_in[0];
  const float* w0   = (const float*)d_in[1];
  const float* x2   = (const float*)d_in[2];
  const float* w2   = (const float*)d_in[3];
  const float* x4   = (const float*)d_in[4];
  const float* w4   = (const float*)d_in[5];
  const float* x6   = (const float*)d_in[6];
  const float* w6   = (const float*)d_in[7];
  const float* x8   = (const float*)d_in[8];
  const float* w8   = (const float*)d_in[9];
  const float* bias = (const float*)d_in[10];
  float* out = (float*)d_out;

  s2_prep<<<dim3(42*32), dim3(128), 0, stream>>>(w2,w4,w6,w8, g_dev.d_cg, g_dev.d_v);
  s2_main<<<dim3(2048), dim3(WGB), 0, stream>>>(x0,x2,x4,x6,x8, w0, bias,
                                                g_dev.d_cg, g_dev.d_wiU,
                                                g_dev.d_v, out, g_dev.c000);
}